// Round 9
// baseline (3057.592 us; speedup 1.0000x reference)
//
#include <hip/hip_runtime.h>
#include <math.h>

// MACE layer, f32. Round 14: single-knob experiment. R13 (CE=32, LDS 18.4KB,
// VGPR 68) should allow 7 blocks/CU (87.5% occ) but measured occupancy was
// PINNED at 34% -- identical to R12 (LDS 32KB, 5-block cap). Static resources
// are not the binder. Correlation across the session: kernels with
// launch_bounds(...,4+) achieved ~46% occ (R8, R10, R11 k_tp); all (.,2)
// kernels sit at 34-35% (R9/R12/R13). Test: R13 verbatim, launch_bounds
// (256,2) -> (256,7). 7 waves/EU implies 72-VGPR budget; R13 uses 68 <= 72
// so codegen should be unchanged (no R10-style forced spill). Tripwires:
// VGPR 68, WRITE ~96MB. If occ/duration unchanged -> hypothesis falsified,
// next lever is w4-traffic halving (CE=64 + path-split ev).
// K1: node pre   Ksort: hist/scan/permute   K2: fused edge   K3: epilogue

#define N_NODES 32768
#define N_EDGES 524288
#define FCH 128
#define NBASIS 8
#define HDIM 64
#define CE 32      // edges per block in K2 (N_EDGES = 16384 * CE exactly)
#define NWIN 4     // receiver-node LDS window
#define NT1 8      // nodes per block in K1/K3
#define MIXW 640   // NP * FCH (w4 row stride)

__device__ __forceinline__ float silu(float x) { return x / (1.0f + __expf(-x)); }

constexpr float INV_SQRT128  = 0.08838834764831845f;
constexpr float INV_SQRT8    = 0.35355339059327373f;
constexpr float INV_64       = 0.125f;                 // 1/sqrt(64)
constexpr float INV_SQRT10   = 0.31622776601683794f;
constexpr float INV_SQRT1280 = 0.027950849718747374f;  // 1/sqrt(F*Z)
constexpr float INV_SQRT16   = 0.25f;
constexpr float EPSN         = 0.125f;
constexpr float C_P1         = 0.07216878364870323f;   // INV_SQRT3 * INV_64
constexpr float C_P4         = 0.08838834764831845f;   // INV_SQRT2 * INV_64

// ---------------------------------------------------------------- K1: node pre
__global__ __launch_bounds__(128) void k_node_pre(
    const float* __restrict__ ns, const float* __restrict__ nv,
    const float* __restrict__ w_skip, const float* __restrict__ w_up0,
    const float* __restrict__ w_up1, const int* __restrict__ species,
    float* __restrict__ hs, float* __restrict__ hv0, float* __restrict__ hv1,
    float* __restrict__ hv2, float* __restrict__ self_conn)
{
    __shared__ float ls[NT1][FCH];
    __shared__ float lv[3][NT1][FCH];
    __shared__ int lsp[NT1];
    const int g  = threadIdx.x;
    const int n0 = blockIdx.x * NT1;

    #pragma unroll
    for (int n = 0; n < NT1; ++n)
        ls[n][g] = ns[(size_t)(n0 + n) * FCH + g];
    for (int idx = g; idx < NT1 * FCH; idx += 128) {
        int n = idx >> 7, f = idx & 127;
        const float* src = nv + ((size_t)(n0 + n) * FCH + f) * 3;
        lv[0][n][f] = src[0];
        lv[1][n][f] = src[1];
        lv[2][n][f] = src[2];
    }
    if (g < NT1) lsp[g] = species[n0 + g];
    __syncthreads();

    const float* wk[NT1];
    #pragma unroll
    for (int n = 0; n < NT1; ++n)
        wk[n] = w_skip + (size_t)lsp[n] * FCH * FCH + g;

    float a_s[NT1], a0[NT1], a1[NT1], a2[NT1], a_k[NT1];
    #pragma unroll
    for (int n = 0; n < NT1; ++n) { a_s[n]=0; a0[n]=0; a1[n]=0; a2[n]=0; a_k[n]=0; }

    #pragma unroll 2
    for (int f = 0; f < FCH; ++f) {
        float u0 = w_up0[f * FCH + g];
        float u1 = w_up1[f * FCH + g];
        #pragma unroll
        for (int n = 0; n < NT1; ++n) {
            float s = ls[n][f];
            a_s[n] += s * u0;
            a0[n]  += lv[0][n][f] * u1;
            a1[n]  += lv[1][n][f] * u1;
            a2[n]  += lv[2][n][f] * u1;
            a_k[n] += s * wk[n][(size_t)f * FCH];
        }
    }
    #pragma unroll
    for (int n = 0; n < NT1; ++n) {
        size_t o = (size_t)(n0 + n) * FCH + g;
        hs[o]  = a_s[n] * INV_SQRT128;
        hv0[o] = a0[n]  * INV_SQRT128;
        hv1[o] = a1[n]  * INV_SQRT128;
        hv2[o] = a2[n]  * INV_SQRT128;
        self_conn[o] = a_k[n] * INV_SQRT1280;
    }
}

// ---------------------------------------------------------------- sort kernels
__global__ __launch_bounds__(256) void k_hist(
    const int* __restrict__ recv, int* __restrict__ counts)
{
    int e = blockIdx.x * 256 + threadIdx.x;
    atomicAdd(&counts[recv[e]], 1);
}

__global__ __launch_bounds__(1024) void k_scan(
    const int* __restrict__ counts, int* __restrict__ cursor)
{
    __shared__ int part[1024];
    const int t  = threadIdx.x;
    const int b0 = t * 32;
    int local[32];
    int s = 0;
    #pragma unroll
    for (int i = 0; i < 32; ++i) { local[i] = s; s += counts[b0 + i]; }
    part[t] = s;
    __syncthreads();
    for (int off = 1; off < 1024; off <<= 1) {
        int v   = part[t];
        int add = (t >= off) ? part[t - off] : 0;
        __syncthreads();
        part[t] = v + add;
        __syncthreads();
    }
    int base = (t == 0) ? 0 : part[t - 1];
    #pragma unroll
    for (int i = 0; i < 32; ++i) cursor[b0 + i] = base + local[i];
}

__global__ __launch_bounds__(256) void k_permute(
    const int* __restrict__ recv, int* __restrict__ cursor,
    int* __restrict__ perm)
{
    int e = blockIdx.x * 256 + threadIdx.x;
    int pos = atomicAdd(&cursor[recv[e]], 1);
    perm[pos] = e;
}

// flush macros (all indices compile-time; named scalar accumulators)
#define FLUSH_ES()                                                        \
    do {                                                                  \
        if (cur < NWIN) {                                                 \
            const int b_ = cur * FCH + fq;                                \
            atomicAdd(&laccS[b_+0], aS0); atomicAdd(&laccS[b_+1], aS1);   \
            atomicAdd(&laccS[b_+2], aS2); atomicAdd(&laccS[b_+3], aS3);   \
            atomicAdd(&laccV0[b_+0], aV00); atomicAdd(&laccV0[b_+1], aV01);\
            atomicAdd(&laccV0[b_+2], aV02); atomicAdd(&laccV0[b_+3], aV03);\
            atomicAdd(&laccV1[b_+0], aV10); atomicAdd(&laccV1[b_+1], aV11);\
            atomicAdd(&laccV1[b_+2], aV12); atomicAdd(&laccV1[b_+3], aV13);\
            atomicAdd(&laccV2[b_+0], aV20); atomicAdd(&laccV2[b_+1], aV21);\
            atomicAdd(&laccV2[b_+2], aV22); atomicAdd(&laccV2[b_+3], aV23);\
        } else {                                                          \
            const size_t g_ = (size_t)(r0 + cur) * FCH + fq;              \
            atomicAdd(&agg_s[g_+0], aS0); atomicAdd(&agg_s[g_+1], aS1);   \
            atomicAdd(&agg_s[g_+2], aS2); atomicAdd(&agg_s[g_+3], aS3);   \
            atomicAdd(&agg_v0[g_+0], aV00); atomicAdd(&agg_v0[g_+1], aV01);\
            atomicAdd(&agg_v0[g_+2], aV02); atomicAdd(&agg_v0[g_+3], aV03);\
            atomicAdd(&agg_v1[g_+0], aV10); atomicAdd(&agg_v1[g_+1], aV11);\
            atomicAdd(&agg_v1[g_+2], aV12); atomicAdd(&agg_v1[g_+3], aV13);\
            atomicAdd(&agg_v2[g_+0], aV20); atomicAdd(&agg_v2[g_+1], aV21);\
            atomicAdd(&agg_v2[g_+2], aV22); atomicAdd(&agg_v2[g_+3], aV23);\
        }                                                                 \
    } while (0)

#define ZERO_ACC()                                                        \
    do { aS0=0;aS1=0;aS2=0;aS3=0; aV00=0;aV01=0;aV02=0;aV03=0;            \
         aV10=0;aV11=0;aV12=0;aV13=0; aV20=0;aV21=0;aV22=0;aV23=0; } while (0)

// ---------------------------------------------------------------- K2: fused
// Block = 32 receiver-sorted edges. MLP wave-private (8 rows/wave) in-place
// in LDS hA. es-group: paths 0,2 over the group's 4 edges; ev-group: paths
// 1,3,4 over the same 4 edges (single pass). Segmented register TP flush
// into 4-node LDS window / global overflow. LDS ~17.9KB.
__global__ __launch_bounds__(256, 7) void k_edge(
    const float* __restrict__ vectors, const float* __restrict__ radial,
    const float* __restrict__ w1, const float* __restrict__ w2,
    const float* __restrict__ w3, const float* __restrict__ w4,
    const float* __restrict__ hs, const float* __restrict__ hv0,
    const float* __restrict__ hv1, const float* __restrict__ hv2,
    const int* __restrict__ senders, const int* __restrict__ receivers,
    const int* __restrict__ perm,
    float* __restrict__ agg_s, float* __restrict__ agg_v0,
    float* __restrict__ agg_v1, float* __restrict__ agg_v2)
{
    __shared__ __align__(16) float lrad[CE * NBASIS];  // 1KB
    __shared__ __align__(16) float hA[CE * HDIM];      // 8KB
    __shared__ float lY[CE][3];
    __shared__ int leid[CE], lsend[CE], lrecv[CE];
    __shared__ __align__(16) float laccS[NWIN * FCH];  // 2KB each
    __shared__ __align__(16) float laccV0[NWIN * FCH];
    __shared__ __align__(16) float laccV1[NWIN * FCH];
    __shared__ __align__(16) float laccV2[NWIN * FCH];

    const int tid = threadIdx.x;
    const int p0  = blockIdx.x * CE;

    if (tid < CE) {
        int eid = perm[p0 + tid];
        leid[tid]  = eid;
        lsend[tid] = senders[eid];
        lrecv[tid] = receivers[eid];
        float vx = vectors[(size_t)eid * 3 + 0];
        float vy = vectors[(size_t)eid * 3 + 1];
        float vz = vectors[(size_t)eid * 3 + 2];
        float rn = 1.0f / (sqrtf(vx*vx + vy*vy + vz*vz) + 1e-9f);
        lY[tid][0] = vx * rn; lY[tid][1] = vy * rn; lY[tid][2] = vz * rn;
    }
    for (int i = tid; i < NWIN * FCH; i += 256) {
        laccS[i] = 0.f; laccV0[i] = 0.f; laccV1[i] = 0.f; laccV2[i] = 0.f;
    }
    __syncthreads();
    if (tid < CE * NBASIS)
        lrad[tid] = radial[(size_t)leid[tid >> 3] * NBASIS + (tid & 7)];
    __syncthreads();   // barrier #2 (last before flush)

    // ---- radial MLP, wave-private rows [grp*8, +8), in-place in hA ----
    const int k    = tid & 63;
    const int grp  = tid >> 6;
    const int e_lo = grp * 8;

    {   // layer 1 (8->64)
        float w1c[NBASIS];
        #pragma unroll
        for (int j = 0; j < NBASIS; ++j) w1c[j] = w1[j * HDIM + k];
        #pragma unroll 4
        for (int e = 0; e < 8; ++e) {
            const float* r = &lrad[(e_lo + e) * NBASIS];
            float a = r[0]*w1c[0] + r[1]*w1c[1] + r[2]*w1c[2] + r[3]*w1c[3]
                    + r[4]*w1c[4] + r[5]*w1c[5] + r[6]*w1c[6] + r[7]*w1c[7];
            hA[(e_lo + e) * HDIM + k] = silu(a * INV_SQRT8);
        }
    }
    {   // layer 2 (64->64): j-outer, acc[8]
        float acc[8];
        #pragma unroll
        for (int e = 0; e < 8; ++e) acc[e] = 0.f;
        #pragma unroll 2
        for (int j = 0; j < HDIM; j += 4) {
            float wa = w2[(j+0) * HDIM + k];
            float wb = w2[(j+1) * HDIM + k];
            float wc = w2[(j+2) * HDIM + k];
            float wd = w2[(j+3) * HDIM + k];
            #pragma unroll
            for (int e = 0; e < 8; ++e) {
                float4 h = *(float4*)&hA[(e_lo + e) * HDIM + j];
                acc[e] += h.x*wa + h.y*wb + h.z*wc + h.w*wd;
            }
        }
        #pragma unroll
        for (int e = 0; e < 8; ++e)
            hA[(e_lo + e) * HDIM + k] = silu(acc[e] * INV_64);
    }
    {   // layer 3 (64->64)
        float acc[8];
        #pragma unroll
        for (int e = 0; e < 8; ++e) acc[e] = 0.f;
        #pragma unroll 2
        for (int j = 0; j < HDIM; j += 4) {
            float wa = w3[(j+0) * HDIM + k];
            float wb = w3[(j+1) * HDIM + k];
            float wc = w3[(j+2) * HDIM + k];
            float wd = w3[(j+3) * HDIM + k];
            #pragma unroll
            for (int e = 0; e < 8; ++e) {
                float4 h = *(float4*)&hA[(e_lo + e) * HDIM + j];
                acc[e] += h.x*wa + h.y*wb + h.z*wc + h.w*wd;
            }
        }
        #pragma unroll
        for (int e = 0; e < 8; ++e)
            hA[(e_lo + e) * HDIM + k] = silu(acc[e] * INV_64);
    }

    // ---- operand-grouped path GEMMs + segmented TP (4 edges per group) ----
    const int fq = (tid & 31) * 4;
    const int eg = tid >> 5;
    const int eb = eg * 4;
    const int r0 = lrecv[0];
    const float* w4q = w4 + fq;

    // ===== es-group: paths 0 and 2 over 4 edges =====
    {
        float ma[4][4], mc[4][4];
        #pragma unroll
        for (int q = 0; q < 4; ++q)
            #pragma unroll
            for (int c = 0; c < 4; ++c) { ma[q][c] = 0.f; mc[q][c] = 0.f; }
        #pragma unroll 2
        for (int j = 0; j < HDIM; j += 2) {
            float4 w0a = *(const float4*)(w4q + (size_t)(j+0) * MIXW);
            float4 w0b = *(const float4*)(w4q + (size_t)(j+1) * MIXW);
            float4 w2a = *(const float4*)(w4q + (size_t)(j+0) * MIXW + 2*FCH);
            float4 w2b = *(const float4*)(w4q + (size_t)(j+1) * MIXW + 2*FCH);
            #pragma unroll
            for (int q = 0; q < 4; ++q) {
                float2 h = *(float2*)&hA[(eb + q) * HDIM + j];
                ma[q][0] += h.x*w0a.x + h.y*w0b.x;
                ma[q][1] += h.x*w0a.y + h.y*w0b.y;
                ma[q][2] += h.x*w0a.z + h.y*w0b.z;
                ma[q][3] += h.x*w0a.w + h.y*w0b.w;
                mc[q][0] += h.x*w2a.x + h.y*w2b.x;
                mc[q][1] += h.x*w2a.y + h.y*w2b.y;
                mc[q][2] += h.x*w2a.z + h.y*w2b.z;
                mc[q][3] += h.x*w2a.w + h.y*w2b.w;
            }
        }

        float aS0,aS1,aS2,aS3, aV00,aV01,aV02,aV03;
        float aV10,aV11,aV12,aV13, aV20,aV21,aV22,aV23;
        ZERO_ACC();
        int cur = lrecv[eb] - r0;
        #pragma unroll
        for (int q = 0; q < 4; ++q) {
            const int e  = eb + q;
            const int nl = lrecv[e] - r0;
            if (nl != cur) { FLUSH_ES(); ZERO_ACC(); cur = nl; }
            float4 t4 = *(const float4*)(hs + (size_t)lsend[e] * FCH + fq);
            const float Yx = lY[e][0], Yy = lY[e][1], Yz = lY[e][2];
            aS0 += ma[q][0] * t4.x * INV_64;
            aS1 += ma[q][1] * t4.y * INV_64;
            aS2 += ma[q][2] * t4.z * INV_64;
            aS3 += ma[q][3] * t4.w * INV_64;
            float t0 = mc[q][0] * t4.x * INV_64;
            float t1 = mc[q][1] * t4.y * INV_64;
            float t2 = mc[q][2] * t4.z * INV_64;
            float t3 = mc[q][3] * t4.w * INV_64;
            aV00 += t0*Yx; aV01 += t1*Yx; aV02 += t2*Yx; aV03 += t3*Yx;
            aV10 += t0*Yy; aV11 += t1*Yy; aV12 += t2*Yy; aV13 += t3*Yy;
            aV20 += t0*Yz; aV21 += t1*Yz; aV22 += t2*Yz; aV23 += t3*Yz;
        }
        FLUSH_ES();
    }

    // ===== ev-group: paths 1,3,4 over the same 4 edges (single pass) =====
    {
        float m1[4][4], m3[4][4], m5[4][4];
        #pragma unroll
        for (int q = 0; q < 4; ++q)
            #pragma unroll
            for (int c = 0; c < 4; ++c) { m1[q][c]=0.f; m3[q][c]=0.f; m5[q][c]=0.f; }
        #pragma unroll 4
        for (int j = 0; j < HDIM; ++j) {
            float4 wa1 = *(const float4*)(w4q + (size_t)j * MIXW + 1*FCH);
            float4 wa3 = *(const float4*)(w4q + (size_t)j * MIXW + 3*FCH);
            float4 wa4 = *(const float4*)(w4q + (size_t)j * MIXW + 4*FCH);
            #pragma unroll
            for (int q = 0; q < 4; ++q) {
                float h = hA[(eb + q) * HDIM + j];
                m1[q][0] += h*wa1.x; m1[q][1] += h*wa1.y;
                m1[q][2] += h*wa1.z; m1[q][3] += h*wa1.w;
                m3[q][0] += h*wa3.x; m3[q][1] += h*wa3.y;
                m3[q][2] += h*wa3.z; m3[q][3] += h*wa3.w;
                m5[q][0] += h*wa4.x; m5[q][1] += h*wa4.y;
                m5[q][2] += h*wa4.z; m5[q][3] += h*wa4.w;
            }
        }

        float aS0,aS1,aS2,aS3, aV00,aV01,aV02,aV03;
        float aV10,aV11,aV12,aV13, aV20,aV21,aV22,aV23;
        ZERO_ACC();
        int cur = lrecv[eb] - r0;
        #pragma unroll
        for (int q = 0; q < 4; ++q) {
            const int e  = eb + q;
            const int nl = lrecv[e] - r0;
            if (nl != cur) { FLUSH_ES(); ZERO_ACC(); cur = nl; }
            const size_t so = (size_t)lsend[e] * FCH + fq;
            float4 t0 = *(const float4*)(hv0 + so);
            float4 t1 = *(const float4*)(hv1 + so);
            float4 t2 = *(const float4*)(hv2 + so);
            const float Yx = lY[e][0], Yy = lY[e][1], Yz = lY[e][2];
            {   // c=0
                float d   = t0.x*Yx + t1.x*Yy + t2.x*Yz;
                float m3v = m3[q][0] * INV_64;
                float m4v = m5[q][0] * C_P4;
                aS0  += m1[q][0] * d * C_P1;
                aV00 += m3v*t0.x + m4v*(t1.x*Yz - t2.x*Yy);
                aV10 += m3v*t1.x + m4v*(t2.x*Yx - t0.x*Yz);
                aV20 += m3v*t2.x + m4v*(t0.x*Yy - t1.x*Yx);
            }
            {   // c=1
                float d   = t0.y*Yx + t1.y*Yy + t2.y*Yz;
                float m3v = m3[q][1] * INV_64;
                float m4v = m5[q][1] * C_P4;
                aS1  += m1[q][1] * d * C_P1;
                aV01 += m3v*t0.y + m4v*(t1.y*Yz - t2.y*Yy);
                aV11 += m3v*t1.y + m4v*(t2.y*Yx - t0.y*Yz);
                aV21 += m3v*t2.y + m4v*(t0.y*Yy - t1.y*Yx);
            }
            {   // c=2
                float d   = t0.z*Yx + t1.z*Yy + t2.z*Yz;
                float m3v = m3[q][2] * INV_64;
                float m4v = m5[q][2] * C_P4;
                aS2  += m1[q][2] * d * C_P1;
                aV02 += m3v*t0.z + m4v*(t1.z*Yz - t2.z*Yy);
                aV12 += m3v*t1.z + m4v*(t2.z*Yx - t0.z*Yz);
                aV22 += m3v*t2.z + m4v*(t0.z*Yy - t1.z*Yx);
            }
            {   // c=3
                float d   = t0.w*Yx + t1.w*Yy + t2.w*Yz;
                float m3v = m3[q][3] * INV_64;
                float m4v = m5[q][3] * C_P4;
                aS3  += m1[q][3] * d * C_P1;
                aV03 += m3v*t0.w + m4v*(t1.w*Yz - t2.w*Yy);
                aV13 += m3v*t1.w + m4v*(t2.w*Yx - t0.w*Yz);
                aV23 += m3v*t2.w + m4v*(t0.w*Yy - t1.w*Yx);
            }
        }
        FLUSH_ES();
    }

    __syncthreads();   // barrier #3: window complete
    int span = lrecv[CE - 1] - r0;
    if (span > NWIN - 1) span = NWIN - 1;
    const int tot = (span + 1) * FCH;
    for (int i = tid; i < tot; i += 256) {
        const size_t go = (size_t)(r0 + (i >> 7)) * FCH + (i & 127);
        atomicAdd(&agg_s[go],  laccS[i]);
        atomicAdd(&agg_v0[go], laccV0[i]);
        atomicAdd(&agg_v1[go], laccV1[i]);
        atomicAdd(&agg_v2[go], laccV2[i]);
    }
}

// ---------------------------------------------------------------- K3: epilogue
__global__ __launch_bounds__(128) void k_epilogue(
    const float* __restrict__ agg_s, const float* __restrict__ agg_v0,
    const float* __restrict__ agg_v1, const float* __restrict__ agg_v2,
    const float* __restrict__ self_conn, const int* __restrict__ species,
    const float* __restrict__ w_down0, const float* __restrict__ w_down1,
    const float* __restrict__ w_sc, const float* __restrict__ w_post,
    const float* __restrict__ w_read1, const float* __restrict__ w_read2,
    float* __restrict__ out0, float* __restrict__ feats_out)
{
    __shared__ float lS[NT1][FCH];
    __shared__ float lV[3][NT1][FCH];
    __shared__ float fA[NT1][FCH];
    __shared__ float fB[NT1][FCH];
    __shared__ int lsp[NT1];
    const int g  = threadIdx.x;
    const int n0 = blockIdx.x * NT1;

    #pragma unroll
    for (int n = 0; n < NT1; ++n) {
        size_t o = (size_t)(n0 + n) * FCH + g;
        lS[n][g]    = agg_s[o]  * EPSN;
        lV[0][n][g] = agg_v0[o] * EPSN;
        lV[1][n][g] = agg_v1[o] * EPSN;
        lV[2][n][g] = agg_v2[o] * EPSN;
    }
    if (g < NT1) lsp[g] = species[n0 + g];
    __syncthreads();

    float xs[NT1], xv0[NT1], xv1[NT1], xv2[NT1];
    #pragma unroll
    for (int n = 0; n < NT1; ++n) { xs[n]=0; xv0[n]=0; xv1[n]=0; xv2[n]=0; }
    #pragma unroll 2
    for (int f = 0; f < FCH; ++f) {
        float d0 = w_down0[f * FCH + g];
        float d1 = w_down1[f * FCH + g];
        #pragma unroll
        for (int n = 0; n < NT1; ++n) {
            xs[n]  += lS[n][f] * d0;
            xv0[n] += lV[0][n][f] * d1;
            xv1[n] += lV[1][n][f] * d1;
            xv2[n] += lV[2][n][f] * d1;
        }
    }
    #pragma unroll
    for (int n = 0; n < NT1; ++n) {
        float s  = xs[n]  * INV_SQRT128;
        float v0 = xv0[n] * INV_SQRT128;
        float v1 = xv1[n] * INV_SQRT128;
        float v2 = xv2[n] * INV_SQRT128;
        int z = lsp[n];
        float wz0 = w_sc[((size_t)z * 3 + 0) * FCH + g] * INV_SQRT10;
        float wz1 = w_sc[((size_t)z * 3 + 1) * FCH + g] * INV_SQRT10;
        float wz2 = w_sc[((size_t)z * 3 + 2) * FCH + g] * INV_SQRT10;
        fA[n][g] = wz0 * s + wz1 * s * s + wz2 * (v0*v0 + v1*v1 + v2*v2);
    }
    __syncthreads();

    float fc[NT1];
    #pragma unroll
    for (int n = 0; n < NT1; ++n) fc[n] = 0;
    #pragma unroll 2
    for (int f = 0; f < FCH; ++f) {
        float wp = w_post[f * FCH + g];
        #pragma unroll
        for (int n = 0; n < NT1; ++n) fc[n] += fA[n][f] * wp;
    }
    #pragma unroll
    for (int n = 0; n < NT1; ++n) {
        size_t o = (size_t)(n0 + n) * FCH + g;
        float v = fc[n] * INV_SQRT128 + self_conn[o];
        fB[n][g] = v;
        feats_out[o] = v;
    }
    __syncthreads();

    const int n2 = g >> 4, r = g & 15;
    float acc = 0.f;
    for (int f = 0; f < FCH; ++f) acc += fB[n2][f] * w_read1[f * 16 + r];
    float t = silu(acc * INV_SQRT128);
    float val = t * w_read2[r];
    val += __shfl_down(val, 8, 16);
    val += __shfl_down(val, 4, 16);
    val += __shfl_down(val, 2, 16);
    val += __shfl_down(val, 1, 16);
    if (r == 0) out0[n0 + n2] = val * INV_SQRT16;
}

// ---------------------------------------------------------------- launch
extern "C" void kernel_launch(void* const* d_in, const int* in_sizes, int n_in,
                              void* d_out, int out_size, void* d_ws, size_t ws_size,
                              hipStream_t stream) {
    (void)in_sizes; (void)n_in; (void)out_size; (void)ws_size;
    const float* vectors      = (const float*)d_in[0];
    const float* node_scalars = (const float*)d_in[1];
    const float* node_vectors = (const float*)d_in[2];
    const float* radial       = (const float*)d_in[3];
    const float* w_skip       = (const float*)d_in[4];
    const float* w_up0        = (const float*)d_in[5];
    const float* w_up1        = (const float*)d_in[6];
    const float* mlp_w1       = (const float*)d_in[7];
    const float* mlp_w2       = (const float*)d_in[8];
    const float* mlp_w3       = (const float*)d_in[9];
    const float* mlp_w4       = (const float*)d_in[10];
    const float* w_down0      = (const float*)d_in[11];
    const float* w_down1      = (const float*)d_in[12];
    const float* w_sc         = (const float*)d_in[13];
    const float* w_post       = (const float*)d_in[14];
    const float* w_read1      = (const float*)d_in[15];
    const float* w_read2      = (const float*)d_in[16];
    const int*   senders      = (const int*)d_in[17];
    const int*   receivers    = (const int*)d_in[18];
    const int*   species      = (const int*)d_in[19];

    const size_t NF = (size_t)N_NODES * FCH;
    float* ws     = (float*)d_ws;
    float* hs     = ws;
    float* hv0    = ws + 1 * NF;
    float* hv1    = ws + 2 * NF;
    float* hv2    = ws + 3 * NF;
    float* agg_s  = ws + 4 * NF;
    float* agg_v0 = ws + 5 * NF;
    float* agg_v1 = ws + 6 * NF;
    float* agg_v2 = ws + 7 * NF;
    int* counts   = (int*)(ws + 8 * NF);      // [N]
    int* cursor   = counts + N_NODES;         // [N]
    int* perm     = cursor + N_NODES;         // [E]

    float* out       = (float*)d_out;
    float* feats     = out + N_NODES;   // final feats output
    float* self_conn = feats;           // scratch until epilogue overwrites

    hipMemsetAsync(counts, 0, N_NODES * sizeof(int), stream);
    hipMemsetAsync(agg_s, 0, 4 * NF * sizeof(float), stream);

    k_node_pre<<<N_NODES / NT1, 128, 0, stream>>>(
        node_scalars, node_vectors, w_skip, w_up0, w_up1, species,
        hs, hv0, hv1, hv2, self_conn);

    k_hist<<<N_EDGES / 256, 256, 0, stream>>>(receivers, counts);
    k_scan<<<1, 1024, 0, stream>>>(counts, cursor);
    k_permute<<<N_EDGES / 256, 256, 0, stream>>>(receivers, cursor, perm);

    k_edge<<<N_EDGES / CE, 256, 0, stream>>>(
        vectors, radial, mlp_w1, mlp_w2, mlp_w3, mlp_w4,
        hs, hv0, hv1, hv2, senders, receivers, perm,
        agg_s, agg_v0, agg_v1, agg_v2);

    k_epilogue<<<N_NODES / NT1, 128, 0, stream>>>(
        agg_s, agg_v0, agg_v1, agg_v2, self_conn, species,
        w_down0, w_down1, w_sc, w_post, w_read1, w_read2,
        out, feats);
}

// Round 10
// 2178.838 us; speedup vs baseline: 1.4033x; 1.4033x over previous
//
#include <hip/hip_runtime.h>
#include <math.h>

// MACE layer, f32. Round 15: R14 proved the occupancy mechanism. (256,7)
// forced occ 34->80% but clamped VGPR 68->36 with 3.7GB spill (dur 2901).
// Session-wide model: HW VGPR quantum is 64 (m68/m69) -- 68 VGPR costs the
// same as 128 (4 waves/SIMD, 50% cap, achieved 34%); <=64 -> 8 waves (R8/R11
// 46%, R14 80%). R13 sits 4 regs over the cliff. Fix: NATURALLY cut peak
// pressure below 64 under launch_bounds(256,2) (proven-clean codegen): both
// path-group GEMMs run in 2-edge subpasses (es accs 32->16, ev 48->24);
// the 16 flush accumulators + receiver segmentation persist across
// subpasses. Cost: w4 rows re-read once more per group (~2.7GB L2, ~80us,
// overlapped). Tripwires: VGPR <= 64 (success criterion), WRITE ~96MB.
// K1: node pre   Ksort: hist/scan/permute   K2: fused edge   K3: epilogue

#define N_NODES 32768
#define N_EDGES 524288
#define FCH 128
#define NBASIS 8
#define HDIM 64
#define CE 32      // edges per block in K2 (N_EDGES = 16384 * CE exactly)
#define NWIN 4     // receiver-node LDS window
#define NT1 8      // nodes per block in K1/K3
#define MIXW 640   // NP * FCH (w4 row stride)

__device__ __forceinline__ float silu(float x) { return x / (1.0f + __expf(-x)); }

constexpr float INV_SQRT128  = 0.08838834764831845f;
constexpr float INV_SQRT8    = 0.35355339059327373f;
constexpr float INV_64       = 0.125f;                 // 1/sqrt(64)
constexpr float INV_SQRT10   = 0.31622776601683794f;
constexpr float INV_SQRT1280 = 0.027950849718747374f;  // 1/sqrt(F*Z)
constexpr float INV_SQRT16   = 0.25f;
constexpr float EPSN         = 0.125f;
constexpr float C_P1         = 0.07216878364870323f;   // INV_SQRT3 * INV_64
constexpr float C_P4         = 0.08838834764831845f;   // INV_SQRT2 * INV_64

// ---------------------------------------------------------------- K1: node pre
__global__ __launch_bounds__(128) void k_node_pre(
    const float* __restrict__ ns, const float* __restrict__ nv,
    const float* __restrict__ w_skip, const float* __restrict__ w_up0,
    const float* __restrict__ w_up1, const int* __restrict__ species,
    float* __restrict__ hs, float* __restrict__ hv0, float* __restrict__ hv1,
    float* __restrict__ hv2, float* __restrict__ self_conn)
{
    __shared__ float ls[NT1][FCH];
    __shared__ float lv[3][NT1][FCH];
    __shared__ int lsp[NT1];
    const int g  = threadIdx.x;
    const int n0 = blockIdx.x * NT1;

    #pragma unroll
    for (int n = 0; n < NT1; ++n)
        ls[n][g] = ns[(size_t)(n0 + n) * FCH + g];
    for (int idx = g; idx < NT1 * FCH; idx += 128) {
        int n = idx >> 7, f = idx & 127;
        const float* src = nv + ((size_t)(n0 + n) * FCH + f) * 3;
        lv[0][n][f] = src[0];
        lv[1][n][f] = src[1];
        lv[2][n][f] = src[2];
    }
    if (g < NT1) lsp[g] = species[n0 + g];
    __syncthreads();

    const float* wk[NT1];
    #pragma unroll
    for (int n = 0; n < NT1; ++n)
        wk[n] = w_skip + (size_t)lsp[n] * FCH * FCH + g;

    float a_s[NT1], a0[NT1], a1[NT1], a2[NT1], a_k[NT1];
    #pragma unroll
    for (int n = 0; n < NT1; ++n) { a_s[n]=0; a0[n]=0; a1[n]=0; a2[n]=0; a_k[n]=0; }

    #pragma unroll 2
    for (int f = 0; f < FCH; ++f) {
        float u0 = w_up0[f * FCH + g];
        float u1 = w_up1[f * FCH + g];
        #pragma unroll
        for (int n = 0; n < NT1; ++n) {
            float s = ls[n][f];
            a_s[n] += s * u0;
            a0[n]  += lv[0][n][f] * u1;
            a1[n]  += lv[1][n][f] * u1;
            a2[n]  += lv[2][n][f] * u1;
            a_k[n] += s * wk[n][(size_t)f * FCH];
        }
    }
    #pragma unroll
    for (int n = 0; n < NT1; ++n) {
        size_t o = (size_t)(n0 + n) * FCH + g;
        hs[o]  = a_s[n] * INV_SQRT128;
        hv0[o] = a0[n]  * INV_SQRT128;
        hv1[o] = a1[n]  * INV_SQRT128;
        hv2[o] = a2[n]  * INV_SQRT128;
        self_conn[o] = a_k[n] * INV_SQRT1280;
    }
}

// ---------------------------------------------------------------- sort kernels
__global__ __launch_bounds__(256) void k_hist(
    const int* __restrict__ recv, int* __restrict__ counts)
{
    int e = blockIdx.x * 256 + threadIdx.x;
    atomicAdd(&counts[recv[e]], 1);
}

__global__ __launch_bounds__(1024) void k_scan(
    const int* __restrict__ counts, int* __restrict__ cursor)
{
    __shared__ int part[1024];
    const int t  = threadIdx.x;
    const int b0 = t * 32;
    int local[32];
    int s = 0;
    #pragma unroll
    for (int i = 0; i < 32; ++i) { local[i] = s; s += counts[b0 + i]; }
    part[t] = s;
    __syncthreads();
    for (int off = 1; off < 1024; off <<= 1) {
        int v   = part[t];
        int add = (t >= off) ? part[t - off] : 0;
        __syncthreads();
        part[t] = v + add;
        __syncthreads();
    }
    int base = (t == 0) ? 0 : part[t - 1];
    #pragma unroll
    for (int i = 0; i < 32; ++i) cursor[b0 + i] = base + local[i];
}

__global__ __launch_bounds__(256) void k_permute(
    const int* __restrict__ recv, int* __restrict__ cursor,
    int* __restrict__ perm)
{
    int e = blockIdx.x * 256 + threadIdx.x;
    int pos = atomicAdd(&cursor[recv[e]], 1);
    perm[pos] = e;
}

// flush macros (all indices compile-time; named scalar accumulators)
#define FLUSH_ES()                                                        \
    do {                                                                  \
        if (cur < NWIN) {                                                 \
            const int b_ = cur * FCH + fq;                                \
            atomicAdd(&laccS[b_+0], aS0); atomicAdd(&laccS[b_+1], aS1);   \
            atomicAdd(&laccS[b_+2], aS2); atomicAdd(&laccS[b_+3], aS3);   \
            atomicAdd(&laccV0[b_+0], aV00); atomicAdd(&laccV0[b_+1], aV01);\
            atomicAdd(&laccV0[b_+2], aV02); atomicAdd(&laccV0[b_+3], aV03);\
            atomicAdd(&laccV1[b_+0], aV10); atomicAdd(&laccV1[b_+1], aV11);\
            atomicAdd(&laccV1[b_+2], aV12); atomicAdd(&laccV1[b_+3], aV13);\
            atomicAdd(&laccV2[b_+0], aV20); atomicAdd(&laccV2[b_+1], aV21);\
            atomicAdd(&laccV2[b_+2], aV22); atomicAdd(&laccV2[b_+3], aV23);\
        } else {                                                          \
            const size_t g_ = (size_t)(r0 + cur) * FCH + fq;              \
            atomicAdd(&agg_s[g_+0], aS0); atomicAdd(&agg_s[g_+1], aS1);   \
            atomicAdd(&agg_s[g_+2], aS2); atomicAdd(&agg_s[g_+3], aS3);   \
            atomicAdd(&agg_v0[g_+0], aV00); atomicAdd(&agg_v0[g_+1], aV01);\
            atomicAdd(&agg_v0[g_+2], aV02); atomicAdd(&agg_v0[g_+3], aV03);\
            atomicAdd(&agg_v1[g_+0], aV10); atomicAdd(&agg_v1[g_+1], aV11);\
            atomicAdd(&agg_v1[g_+2], aV12); atomicAdd(&agg_v1[g_+3], aV13);\
            atomicAdd(&agg_v2[g_+0], aV20); atomicAdd(&agg_v2[g_+1], aV21);\
            atomicAdd(&agg_v2[g_+2], aV22); atomicAdd(&agg_v2[g_+3], aV23);\
        }                                                                 \
    } while (0)

#define ZERO_ACC()                                                        \
    do { aS0=0;aS1=0;aS2=0;aS3=0; aV00=0;aV01=0;aV02=0;aV03=0;            \
         aV10=0;aV11=0;aV12=0;aV13=0; aV20=0;aV21=0;aV22=0;aV23=0; } while (0)

// ---------------------------------------------------------------- K2: fused
// Block = 32 receiver-sorted edges. MLP wave-private (8 rows/wave) in-place
// in LDS hA. Path GEMMs in 2-edge subpasses (low register peak); the 16
// flush accumulators + receiver segmentation persist across subpasses.
// 4-node LDS window + global overflow. LDS ~17.9KB.
__global__ __launch_bounds__(256, 2) void k_edge(
    const float* __restrict__ vectors, const float* __restrict__ radial,
    const float* __restrict__ w1, const float* __restrict__ w2,
    const float* __restrict__ w3, const float* __restrict__ w4,
    const float* __restrict__ hs, const float* __restrict__ hv0,
    const float* __restrict__ hv1, const float* __restrict__ hv2,
    const int* __restrict__ senders, const int* __restrict__ receivers,
    const int* __restrict__ perm,
    float* __restrict__ agg_s, float* __restrict__ agg_v0,
    float* __restrict__ agg_v1, float* __restrict__ agg_v2)
{
    __shared__ __align__(16) float lrad[CE * NBASIS];  // 1KB
    __shared__ __align__(16) float hA[CE * HDIM];      // 8KB
    __shared__ float lY[CE][3];
    __shared__ int leid[CE], lsend[CE], lrecv[CE];
    __shared__ __align__(16) float laccS[NWIN * FCH];  // 2KB each
    __shared__ __align__(16) float laccV0[NWIN * FCH];
    __shared__ __align__(16) float laccV1[NWIN * FCH];
    __shared__ __align__(16) float laccV2[NWIN * FCH];

    const int tid = threadIdx.x;
    const int p0  = blockIdx.x * CE;

    if (tid < CE) {
        int eid = perm[p0 + tid];
        leid[tid]  = eid;
        lsend[tid] = senders[eid];
        lrecv[tid] = receivers[eid];
        float vx = vectors[(size_t)eid * 3 + 0];
        float vy = vectors[(size_t)eid * 3 + 1];
        float vz = vectors[(size_t)eid * 3 + 2];
        float rn = 1.0f / (sqrtf(vx*vx + vy*vy + vz*vz) + 1e-9f);
        lY[tid][0] = vx * rn; lY[tid][1] = vy * rn; lY[tid][2] = vz * rn;
    }
    for (int i = tid; i < NWIN * FCH; i += 256) {
        laccS[i] = 0.f; laccV0[i] = 0.f; laccV1[i] = 0.f; laccV2[i] = 0.f;
    }
    __syncthreads();
    if (tid < CE * NBASIS)
        lrad[tid] = radial[(size_t)leid[tid >> 3] * NBASIS + (tid & 7)];
    __syncthreads();   // barrier #2 (last before flush)

    // ---- radial MLP, wave-private rows [grp*8, +8), in-place in hA ----
    const int k    = tid & 63;
    const int grp  = tid >> 6;
    const int e_lo = grp * 8;

    {   // layer 1 (8->64)
        float w1c[NBASIS];
        #pragma unroll
        for (int j = 0; j < NBASIS; ++j) w1c[j] = w1[j * HDIM + k];
        #pragma unroll 4
        for (int e = 0; e < 8; ++e) {
            const float* r = &lrad[(e_lo + e) * NBASIS];
            float a = r[0]*w1c[0] + r[1]*w1c[1] + r[2]*w1c[2] + r[3]*w1c[3]
                    + r[4]*w1c[4] + r[5]*w1c[5] + r[6]*w1c[6] + r[7]*w1c[7];
            hA[(e_lo + e) * HDIM + k] = silu(a * INV_SQRT8);
        }
    }
    {   // layer 2 (64->64): j-outer, acc[8]
        float acc[8];
        #pragma unroll
        for (int e = 0; e < 8; ++e) acc[e] = 0.f;
        #pragma unroll 2
        for (int j = 0; j < HDIM; j += 4) {
            float wa = w2[(j+0) * HDIM + k];
            float wb = w2[(j+1) * HDIM + k];
            float wc = w2[(j+2) * HDIM + k];
            float wd = w2[(j+3) * HDIM + k];
            #pragma unroll
            for (int e = 0; e < 8; ++e) {
                float4 h = *(float4*)&hA[(e_lo + e) * HDIM + j];
                acc[e] += h.x*wa + h.y*wb + h.z*wc + h.w*wd;
            }
        }
        #pragma unroll
        for (int e = 0; e < 8; ++e)
            hA[(e_lo + e) * HDIM + k] = silu(acc[e] * INV_64);
    }
    {   // layer 3 (64->64)
        float acc[8];
        #pragma unroll
        for (int e = 0; e < 8; ++e) acc[e] = 0.f;
        #pragma unroll 2
        for (int j = 0; j < HDIM; j += 4) {
            float wa = w3[(j+0) * HDIM + k];
            float wb = w3[(j+1) * HDIM + k];
            float wc = w3[(j+2) * HDIM + k];
            float wd = w3[(j+3) * HDIM + k];
            #pragma unroll
            for (int e = 0; e < 8; ++e) {
                float4 h = *(float4*)&hA[(e_lo + e) * HDIM + j];
                acc[e] += h.x*wa + h.y*wb + h.z*wc + h.w*wd;
            }
        }
        #pragma unroll
        for (int e = 0; e < 8; ++e)
            hA[(e_lo + e) * HDIM + k] = silu(acc[e] * INV_64);
    }

    // ---- operand-grouped path GEMMs + segmented TP (2-edge subpasses) ----
    const int fq = (tid & 31) * 4;
    const int eg = tid >> 5;
    const int eb = eg * 4;
    const int r0 = lrecv[0];
    const float* w4q = w4 + fq;

    // ===== es-group: paths 0,2; two 2-edge subpasses share flush accs =====
    {
        float aS0,aS1,aS2,aS3, aV00,aV01,aV02,aV03;
        float aV10,aV11,aV12,aV13, aV20,aV21,aV22,aV23;
        ZERO_ACC();
        int cur = lrecv[eb] - r0;
        #pragma unroll
        for (int sub = 0; sub < 2; ++sub) {
            const int e0 = eb + sub * 2;
            float ma[2][4], mc[2][4];
            #pragma unroll
            for (int q = 0; q < 2; ++q)
                #pragma unroll
                for (int c = 0; c < 4; ++c) { ma[q][c] = 0.f; mc[q][c] = 0.f; }
            #pragma unroll 2
            for (int j = 0; j < HDIM; j += 2) {
                float4 w0a = *(const float4*)(w4q + (size_t)(j+0) * MIXW);
                float4 w0b = *(const float4*)(w4q + (size_t)(j+1) * MIXW);
                float4 w2a = *(const float4*)(w4q + (size_t)(j+0) * MIXW + 2*FCH);
                float4 w2b = *(const float4*)(w4q + (size_t)(j+1) * MIXW + 2*FCH);
                #pragma unroll
                for (int q = 0; q < 2; ++q) {
                    float2 h = *(float2*)&hA[(e0 + q) * HDIM + j];
                    ma[q][0] += h.x*w0a.x + h.y*w0b.x;
                    ma[q][1] += h.x*w0a.y + h.y*w0b.y;
                    ma[q][2] += h.x*w0a.z + h.y*w0b.z;
                    ma[q][3] += h.x*w0a.w + h.y*w0b.w;
                    mc[q][0] += h.x*w2a.x + h.y*w2b.x;
                    mc[q][1] += h.x*w2a.y + h.y*w2b.y;
                    mc[q][2] += h.x*w2a.z + h.y*w2b.z;
                    mc[q][3] += h.x*w2a.w + h.y*w2b.w;
                }
            }
            #pragma unroll
            for (int q = 0; q < 2; ++q) {
                const int e  = e0 + q;
                const int nl = lrecv[e] - r0;
                if (nl != cur) { FLUSH_ES(); ZERO_ACC(); cur = nl; }
                float4 t4 = *(const float4*)(hs + (size_t)lsend[e] * FCH + fq);
                const float Yx = lY[e][0], Yy = lY[e][1], Yz = lY[e][2];
                aS0 += ma[q][0] * t4.x * INV_64;
                aS1 += ma[q][1] * t4.y * INV_64;
                aS2 += ma[q][2] * t4.z * INV_64;
                aS3 += ma[q][3] * t4.w * INV_64;
                float t0 = mc[q][0] * t4.x * INV_64;
                float t1 = mc[q][1] * t4.y * INV_64;
                float t2 = mc[q][2] * t4.z * INV_64;
                float t3 = mc[q][3] * t4.w * INV_64;
                aV00 += t0*Yx; aV01 += t1*Yx; aV02 += t2*Yx; aV03 += t3*Yx;
                aV10 += t0*Yy; aV11 += t1*Yy; aV12 += t2*Yy; aV13 += t3*Yy;
                aV20 += t0*Yz; aV21 += t1*Yz; aV22 += t2*Yz; aV23 += t3*Yz;
            }
        }
        FLUSH_ES();
    }

    // ===== ev-group: paths 1,3,4; two 2-edge subpasses share flush accs =====
    {
        float aS0,aS1,aS2,aS3, aV00,aV01,aV02,aV03;
        float aV10,aV11,aV12,aV13, aV20,aV21,aV22,aV23;
        ZERO_ACC();
        int cur = lrecv[eb] - r0;
        #pragma unroll
        for (int sub = 0; sub < 2; ++sub) {
            const int e0 = eb + sub * 2;
            float m1[2][4], m3[2][4], m5[2][4];
            #pragma unroll
            for (int q = 0; q < 2; ++q)
                #pragma unroll
                for (int c = 0; c < 4; ++c) { m1[q][c]=0.f; m3[q][c]=0.f; m5[q][c]=0.f; }
            #pragma unroll 4
            for (int j = 0; j < HDIM; ++j) {
                float4 wa1 = *(const float4*)(w4q + (size_t)j * MIXW + 1*FCH);
                float4 wa3 = *(const float4*)(w4q + (size_t)j * MIXW + 3*FCH);
                float4 wa4 = *(const float4*)(w4q + (size_t)j * MIXW + 4*FCH);
                #pragma unroll
                for (int q = 0; q < 2; ++q) {
                    float h = hA[(e0 + q) * HDIM + j];
                    m1[q][0] += h*wa1.x; m1[q][1] += h*wa1.y;
                    m1[q][2] += h*wa1.z; m1[q][3] += h*wa1.w;
                    m3[q][0] += h*wa3.x; m3[q][1] += h*wa3.y;
                    m3[q][2] += h*wa3.z; m3[q][3] += h*wa3.w;
                    m5[q][0] += h*wa4.x; m5[q][1] += h*wa4.y;
                    m5[q][2] += h*wa4.z; m5[q][3] += h*wa4.w;
                }
            }
            #pragma unroll
            for (int q = 0; q < 2; ++q) {
                const int e  = e0 + q;
                const int nl = lrecv[e] - r0;
                if (nl != cur) { FLUSH_ES(); ZERO_ACC(); cur = nl; }
                const size_t so = (size_t)lsend[e] * FCH + fq;
                float4 t0 = *(const float4*)(hv0 + so);
                float4 t1 = *(const float4*)(hv1 + so);
                float4 t2 = *(const float4*)(hv2 + so);
                const float Yx = lY[e][0], Yy = lY[e][1], Yz = lY[e][2];
                {   // c=0
                    float d   = t0.x*Yx + t1.x*Yy + t2.x*Yz;
                    float m3v = m3[q][0] * INV_64;
                    float m4v = m5[q][0] * C_P4;
                    aS0  += m1[q][0] * d * C_P1;
                    aV00 += m3v*t0.x + m4v*(t1.x*Yz - t2.x*Yy);
                    aV10 += m3v*t1.x + m4v*(t2.x*Yx - t0.x*Yz);
                    aV20 += m3v*t2.x + m4v*(t0.x*Yy - t1.x*Yx);
                }
                {   // c=1
                    float d   = t0.y*Yx + t1.y*Yy + t2.y*Yz;
                    float m3v = m3[q][1] * INV_64;
                    float m4v = m5[q][1] * C_P4;
                    aS1  += m1[q][1] * d * C_P1;
                    aV01 += m3v*t0.y + m4v*(t1.y*Yz - t2.y*Yy);
                    aV11 += m3v*t1.y + m4v*(t2.y*Yx - t0.y*Yz);
                    aV21 += m3v*t2.y + m4v*(t0.y*Yy - t1.y*Yx);
                }
                {   // c=2
                    float d   = t0.z*Yx + t1.z*Yy + t2.z*Yz;
                    float m3v = m3[q][2] * INV_64;
                    float m4v = m5[q][2] * C_P4;
                    aS2  += m1[q][2] * d * C_P1;
                    aV02 += m3v*t0.z + m4v*(t1.z*Yz - t2.z*Yy);
                    aV12 += m3v*t1.z + m4v*(t2.z*Yx - t0.z*Yz);
                    aV22 += m3v*t2.z + m4v*(t0.z*Yy - t1.z*Yx);
                }
                {   // c=3
                    float d   = t0.w*Yx + t1.w*Yy + t2.w*Yz;
                    float m3v = m3[q][3] * INV_64;
                    float m4v = m5[q][3] * C_P4;
                    aS3  += m1[q][3] * d * C_P1;
                    aV03 += m3v*t0.w + m4v*(t1.w*Yz - t2.w*Yy);
                    aV13 += m3v*t1.w + m4v*(t2.w*Yx - t0.w*Yz);
                    aV23 += m3v*t2.w + m4v*(t0.w*Yy - t1.w*Yx);
                }
            }
        }
        FLUSH_ES();
    }

    __syncthreads();   // barrier #3: window complete
    int span = lrecv[CE - 1] - r0;
    if (span > NWIN - 1) span = NWIN - 1;
    const int tot = (span + 1) * FCH;
    for (int i = tid; i < tot; i += 256) {
        const size_t go = (size_t)(r0 + (i >> 7)) * FCH + (i & 127);
        atomicAdd(&agg_s[go],  laccS[i]);
        atomicAdd(&agg_v0[go], laccV0[i]);
        atomicAdd(&agg_v1[go], laccV1[i]);
        atomicAdd(&agg_v2[go], laccV2[i]);
    }
}

// ---------------------------------------------------------------- K3: epilogue
__global__ __launch_bounds__(128) void k_epilogue(
    const float* __restrict__ agg_s, const float* __restrict__ agg_v0,
    const float* __restrict__ agg_v1, const float* __restrict__ agg_v2,
    const float* __restrict__ self_conn, const int* __restrict__ species,
    const float* __restrict__ w_down0, const float* __restrict__ w_down1,
    const float* __restrict__ w_sc, const float* __restrict__ w_post,
    const float* __restrict__ w_read1, const float* __restrict__ w_read2,
    float* __restrict__ out0, float* __restrict__ feats_out)
{
    __shared__ float lS[NT1][FCH];
    __shared__ float lV[3][NT1][FCH];
    __shared__ float fA[NT1][FCH];
    __shared__ float fB[NT1][FCH];
    __shared__ int lsp[NT1];
    const int g  = threadIdx.x;
    const int n0 = blockIdx.x * NT1;

    #pragma unroll
    for (int n = 0; n < NT1; ++n) {
        size_t o = (size_t)(n0 + n) * FCH + g;
        lS[n][g]    = agg_s[o]  * EPSN;
        lV[0][n][g] = agg_v0[o] * EPSN;
        lV[1][n][g] = agg_v1[o] * EPSN;
        lV[2][n][g] = agg_v2[o] * EPSN;
    }
    if (g < NT1) lsp[g] = species[n0 + g];
    __syncthreads();

    float xs[NT1], xv0[NT1], xv1[NT1], xv2[NT1];
    #pragma unroll
    for (int n = 0; n < NT1; ++n) { xs[n]=0; xv0[n]=0; xv1[n]=0; xv2[n]=0; }
    #pragma unroll 2
    for (int f = 0; f < FCH; ++f) {
        float d0 = w_down0[f * FCH + g];
        float d1 = w_down1[f * FCH + g];
        #pragma unroll
        for (int n = 0; n < NT1; ++n) {
            xs[n]  += lS[n][f] * d0;
            xv0[n] += lV[0][n][f] * d1;
            xv1[n] += lV[1][n][f] * d1;
            xv2[n] += lV[2][n][f] * d1;
        }
    }
    #pragma unroll
    for (int n = 0; n < NT1; ++n) {
        float s  = xs[n]  * INV_SQRT128;
        float v0 = xv0[n] * INV_SQRT128;
        float v1 = xv1[n] * INV_SQRT128;
        float v2 = xv2[n] * INV_SQRT128;
        int z = lsp[n];
        float wz0 = w_sc[((size_t)z * 3 + 0) * FCH + g] * INV_SQRT10;
        float wz1 = w_sc[((size_t)z * 3 + 1) * FCH + g] * INV_SQRT10;
        float wz2 = w_sc[((size_t)z * 3 + 2) * FCH + g] * INV_SQRT10;
        fA[n][g] = wz0 * s + wz1 * s * s + wz2 * (v0*v0 + v1*v1 + v2*v2);
    }
    __syncthreads();

    float fc[NT1];
    #pragma unroll
    for (int n = 0; n < NT1; ++n) fc[n] = 0;
    #pragma unroll 2
    for (int f = 0; f < FCH; ++f) {
        float wp = w_post[f * FCH + g];
        #pragma unroll
        for (int n = 0; n < NT1; ++n) fc[n] += fA[n][f] * wp;
    }
    #pragma unroll
    for (int n = 0; n < NT1; ++n) {
        size_t o = (size_t)(n0 + n) * FCH + g;
        float v = fc[n] * INV_SQRT128 + self_conn[o];
        fB[n][g] = v;
        feats_out[o] = v;
    }
    __syncthreads();

    const int n2 = g >> 4, r = g & 15;
    float acc = 0.f;
    for (int f = 0; f < FCH; ++f) acc += fB[n2][f] * w_read1[f * 16 + r];
    float t = silu(acc * INV_SQRT128);
    float val = t * w_read2[r];
    val += __shfl_down(val, 8, 16);
    val += __shfl_down(val, 4, 16);
    val += __shfl_down(val, 2, 16);
    val += __shfl_down(val, 1, 16);
    if (r == 0) out0[n0 + n2] = val * INV_SQRT16;
}

// ---------------------------------------------------------------- launch
extern "C" void kernel_launch(void* const* d_in, const int* in_sizes, int n_in,
                              void* d_out, int out_size, void* d_ws, size_t ws_size,
                              hipStream_t stream) {
    (void)in_sizes; (void)n_in; (void)out_size; (void)ws_size;
    const float* vectors      = (const float*)d_in[0];
    const float* node_scalars = (const float*)d_in[1];
    const float* node_vectors = (const float*)d_in[2];
    const float* radial       = (const float*)d_in[3];
    const float* w_skip       = (const float*)d_in[4];
    const float* w_up0        = (const float*)d_in[5];
    const float* w_up1        = (const float*)d_in[6];
    const float* mlp_w1       = (const float*)d_in[7];
    const float* mlp_w2       = (const float*)d_in[8];
    const float* mlp_w3       = (const float*)d_in[9];
    const float* mlp_w4       = (const float*)d_in[10];
    const float* w_down0      = (const float*)d_in[11];
    const float* w_down1      = (const float*)d_in[12];
    const float* w_sc         = (const float*)d_in[13];
    const float* w_post       = (const float*)d_in[14];
    const float* w_read1      = (const float*)d_in[15];
    const float* w_read2      = (const float*)d_in[16];
    const int*   senders      = (const int*)d_in[17];
    const int*   receivers    = (const int*)d_in[18];
    const int*   species      = (const int*)d_in[19];

    const size_t NF = (size_t)N_NODES * FCH;
    float* ws     = (float*)d_ws;
    float* hs     = ws;
    float* hv0    = ws + 1 * NF;
    float* hv1    = ws + 2 * NF;
    float* hv2    = ws + 3 * NF;
    float* agg_s  = ws + 4 * NF;
    float* agg_v0 = ws + 5 * NF;
    float* agg_v1 = ws + 6 * NF;
    float* agg_v2 = ws + 7 * NF;
    int* counts   = (int*)(ws + 8 * NF);      // [N]
    int* cursor   = counts + N_NODES;         // [N]
    int* perm     = cursor + N_NODES;         // [E]

    float* out       = (float*)d_out;
    float* feats     = out + N_NODES;   // final feats output
    float* self_conn = feats;           // scratch until epilogue overwrites

    hipMemsetAsync(counts, 0, N_NODES * sizeof(int), stream);
    hipMemsetAsync(agg_s, 0, 4 * NF * sizeof(float), stream);

    k_node_pre<<<N_NODES / NT1, 128, 0, stream>>>(
        node_scalars, node_vectors, w_skip, w_up0, w_up1, species,
        hs, hv0, hv1, hv2, self_conn);

    k_hist<<<N_EDGES / 256, 256, 0, stream>>>(receivers, counts);
    k_scan<<<1, 1024, 0, stream>>>(counts, cursor);
    k_permute<<<N_EDGES / 256, 256, 0, stream>>>(receivers, cursor, perm);

    k_edge<<<N_EDGES / CE, 256, 0, stream>>>(
        vectors, radial, mlp_w1, mlp_w2, mlp_w3, mlp_w4,
        hs, hv0, hv1, hv2, senders, receivers, perm,
        agg_s, agg_v0, agg_v1, agg_v2);

    k_epilogue<<<N_NODES / NT1, 128, 0, stream>>>(
        agg_s, agg_v0, agg_v1, agg_v2, self_conn, species,
        w_down0, w_down1, w_sc, w_post, w_read1, w_read2,
        out, feats);
}

// Round 11
// 2060.144 us; speedup vs baseline: 1.4842x; 1.0576x over previous
//
#include <hip/hip_runtime.h>
#include <math.h>

// MACE layer, f32. Round 16: R15 hit VGPR=64 (occ 34->46%) but 2-edge
// subpasses doubled w4 L2 traffic (Sigma passes 10 -> 21.5GB) -> 1874us.
// Occupancy model now pinned (6 pts): waves/SIMD = floor(256/VGPR), achieved
// ~92% of cap (36->80%, 64->46%, 68->34%). Fix: keep <=64-VGPR discipline,
// restore CE=64 (w4 traffic ~ nBlocks x Sigma path-passes), path-split:
// p0/p2/p1 as 8-edge single-path GEMMs (m[8][4]=32 regs, flush subset only
// 4 or 12 accs), p3/p4 (cross, heaviest) as 4-edge halves. Sigma=7 -> 7.5GB
// w4 L2 (lowest yet; R12 8.6, R13 10.7, R15 21.5). NWIN=6, LDS 32.2KB ->
// 5 blocks/CU (non-binding vs 16-wave VGPR cap).
// Tripwires: VGPR <= 64, WRITE ~96MB.
// K1: node pre   Ksort: hist/scan/permute   K2: fused edge   K3: epilogue

#define N_NODES 32768
#define N_EDGES 524288
#define FCH 128
#define NBASIS 8
#define HDIM 64
#define CE 64      // edges per block in K2 (N_EDGES = 8192 * CE exactly)
#define NWIN 6     // receiver-node LDS window
#define NT1 8      // nodes per block in K1/K3
#define MIXW 640   // NP * FCH (w4 row stride)

__device__ __forceinline__ float silu(float x) { return x / (1.0f + __expf(-x)); }

constexpr float INV_SQRT128  = 0.08838834764831845f;
constexpr float INV_SQRT8    = 0.35355339059327373f;
constexpr float INV_64       = 0.125f;                 // 1/sqrt(64)
constexpr float INV_SQRT10   = 0.31622776601683794f;
constexpr float INV_SQRT1280 = 0.027950849718747374f;  // 1/sqrt(F*Z)
constexpr float INV_SQRT16   = 0.25f;
constexpr float EPSN         = 0.125f;
constexpr float C_P1         = 0.07216878364870323f;   // INV_SQRT3 * INV_64
constexpr float C_P4         = 0.08838834764831845f;   // INV_SQRT2 * INV_64

// ---------------------------------------------------------------- K1: node pre
__global__ __launch_bounds__(128) void k_node_pre(
    const float* __restrict__ ns, const float* __restrict__ nv,
    const float* __restrict__ w_skip, const float* __restrict__ w_up0,
    const float* __restrict__ w_up1, const int* __restrict__ species,
    float* __restrict__ hs, float* __restrict__ hv0, float* __restrict__ hv1,
    float* __restrict__ hv2, float* __restrict__ self_conn)
{
    __shared__ float ls[NT1][FCH];
    __shared__ float lv[3][NT1][FCH];
    __shared__ int lsp[NT1];
    const int g  = threadIdx.x;
    const int n0 = blockIdx.x * NT1;

    #pragma unroll
    for (int n = 0; n < NT1; ++n)
        ls[n][g] = ns[(size_t)(n0 + n) * FCH + g];
    for (int idx = g; idx < NT1 * FCH; idx += 128) {
        int n = idx >> 7, f = idx & 127;
        const float* src = nv + ((size_t)(n0 + n) * FCH + f) * 3;
        lv[0][n][f] = src[0];
        lv[1][n][f] = src[1];
        lv[2][n][f] = src[2];
    }
    if (g < NT1) lsp[g] = species[n0 + g];
    __syncthreads();

    const float* wk[NT1];
    #pragma unroll
    for (int n = 0; n < NT1; ++n)
        wk[n] = w_skip + (size_t)lsp[n] * FCH * FCH + g;

    float a_s[NT1], a0[NT1], a1[NT1], a2[NT1], a_k[NT1];
    #pragma unroll
    for (int n = 0; n < NT1; ++n) { a_s[n]=0; a0[n]=0; a1[n]=0; a2[n]=0; a_k[n]=0; }

    #pragma unroll 2
    for (int f = 0; f < FCH; ++f) {
        float u0 = w_up0[f * FCH + g];
        float u1 = w_up1[f * FCH + g];
        #pragma unroll
        for (int n = 0; n < NT1; ++n) {
            float s = ls[n][f];
            a_s[n] += s * u0;
            a0[n]  += lv[0][n][f] * u1;
            a1[n]  += lv[1][n][f] * u1;
            a2[n]  += lv[2][n][f] * u1;
            a_k[n] += s * wk[n][(size_t)f * FCH];
        }
    }
    #pragma unroll
    for (int n = 0; n < NT1; ++n) {
        size_t o = (size_t)(n0 + n) * FCH + g;
        hs[o]  = a_s[n] * INV_SQRT128;
        hv0[o] = a0[n]  * INV_SQRT128;
        hv1[o] = a1[n]  * INV_SQRT128;
        hv2[o] = a2[n]  * INV_SQRT128;
        self_conn[o] = a_k[n] * INV_SQRT1280;
    }
}

// ---------------------------------------------------------------- sort kernels
__global__ __launch_bounds__(256) void k_hist(
    const int* __restrict__ recv, int* __restrict__ counts)
{
    int e = blockIdx.x * 256 + threadIdx.x;
    atomicAdd(&counts[recv[e]], 1);
}

__global__ __launch_bounds__(1024) void k_scan(
    const int* __restrict__ counts, int* __restrict__ cursor)
{
    __shared__ int part[1024];
    const int t  = threadIdx.x;
    const int b0 = t * 32;
    int local[32];
    int s = 0;
    #pragma unroll
    for (int i = 0; i < 32; ++i) { local[i] = s; s += counts[b0 + i]; }
    part[t] = s;
    __syncthreads();
    for (int off = 1; off < 1024; off <<= 1) {
        int v   = part[t];
        int add = (t >= off) ? part[t - off] : 0;
        __syncthreads();
        part[t] = v + add;
        __syncthreads();
    }
    int base = (t == 0) ? 0 : part[t - 1];
    #pragma unroll
    for (int i = 0; i < 32; ++i) cursor[b0 + i] = base + local[i];
}

__global__ __launch_bounds__(256) void k_permute(
    const int* __restrict__ recv, int* __restrict__ cursor,
    int* __restrict__ perm)
{
    int e = blockIdx.x * 256 + threadIdx.x;
    int pos = atomicAdd(&cursor[recv[e]], 1);
    perm[pos] = e;
}

// flush macros (compile-time register indices; LDS window or global overflow)
#define FLUSH_S()                                                         \
    do {                                                                  \
        if (cur < NWIN) {                                                 \
            const int b_ = cur * FCH + fq;                                \
            atomicAdd(&laccS[b_+0], aS0); atomicAdd(&laccS[b_+1], aS1);   \
            atomicAdd(&laccS[b_+2], aS2); atomicAdd(&laccS[b_+3], aS3);   \
        } else {                                                          \
            const size_t g_ = (size_t)(r0 + cur) * FCH + fq;              \
            atomicAdd(&agg_s[g_+0], aS0); atomicAdd(&agg_s[g_+1], aS1);   \
            atomicAdd(&agg_s[g_+2], aS2); atomicAdd(&agg_s[g_+3], aS3);   \
        }                                                                 \
    } while (0)
#define ZERO_S() do { aS0=0.f;aS1=0.f;aS2=0.f;aS3=0.f; } while (0)

#define FLUSH_V()                                                         \
    do {                                                                  \
        if (cur < NWIN) {                                                 \
            const int b_ = cur * FCH + fq;                                \
            atomicAdd(&laccV0[b_+0], aV00); atomicAdd(&laccV0[b_+1], aV01);\
            atomicAdd(&laccV0[b_+2], aV02); atomicAdd(&laccV0[b_+3], aV03);\
            atomicAdd(&laccV1[b_+0], aV10); atomicAdd(&laccV1[b_+1], aV11);\
            atomicAdd(&laccV1[b_+2], aV12); atomicAdd(&laccV1[b_+3], aV13);\
            atomicAdd(&laccV2[b_+0], aV20); atomicAdd(&laccV2[b_+1], aV21);\
            atomicAdd(&laccV2[b_+2], aV22); atomicAdd(&laccV2[b_+3], aV23);\
        } else {                                                          \
            const size_t g_ = (size_t)(r0 + cur) * FCH + fq;              \
            atomicAdd(&agg_v0[g_+0], aV00); atomicAdd(&agg_v0[g_+1], aV01);\
            atomicAdd(&agg_v0[g_+2], aV02); atomicAdd(&agg_v0[g_+3], aV03);\
            atomicAdd(&agg_v1[g_+0], aV10); atomicAdd(&agg_v1[g_+1], aV11);\
            atomicAdd(&agg_v1[g_+2], aV12); atomicAdd(&agg_v1[g_+3], aV13);\
            atomicAdd(&agg_v2[g_+0], aV20); atomicAdd(&agg_v2[g_+1], aV21);\
            atomicAdd(&agg_v2[g_+2], aV22); atomicAdd(&agg_v2[g_+3], aV23);\
        }                                                                 \
    } while (0)
#define ZERO_V()                                                          \
    do { aV00=0.f;aV01=0.f;aV02=0.f;aV03=0.f; aV10=0.f;aV11=0.f;          \
         aV12=0.f;aV13=0.f; aV20=0.f;aV21=0.f;aV22=0.f;aV23=0.f; } while (0)

// ---------------------------------------------------------------- K2: fused
// Block = 64 receiver-sorted edges. MLP wave-private (16 rows/wave) in-place
// in LDS hA. Five path passes: p0/p2/p1 over 8 edges (m[8][4]), p3/p4 in
// 4-edge halves. Each pass flushes only its acc subset (S or V) per receiver
// segment into the 6-node LDS window / global overflow.
__global__ __launch_bounds__(256, 2) void k_edge(
    const float* __restrict__ vectors, const float* __restrict__ radial,
    const float* __restrict__ w1, const float* __restrict__ w2,
    const float* __restrict__ w3, const float* __restrict__ w4,
    const float* __restrict__ hs, const float* __restrict__ hv0,
    const float* __restrict__ hv1, const float* __restrict__ hv2,
    const int* __restrict__ senders, const int* __restrict__ receivers,
    const int* __restrict__ perm,
    float* __restrict__ agg_s, float* __restrict__ agg_v0,
    float* __restrict__ agg_v1, float* __restrict__ agg_v2)
{
    __shared__ __align__(16) float lrad[CE * NBASIS];  // 2KB
    __shared__ __align__(16) float hA[CE * HDIM];      // 16KB
    __shared__ float lY[CE][3];
    __shared__ int leid[CE], lsend[CE], lrecv[CE];
    __shared__ __align__(16) float laccS[NWIN * FCH];  // 3KB each
    __shared__ __align__(16) float laccV0[NWIN * FCH];
    __shared__ __align__(16) float laccV1[NWIN * FCH];
    __shared__ __align__(16) float laccV2[NWIN * FCH];

    const int tid = threadIdx.x;
    const int p0_ = blockIdx.x * CE;

    if (tid < CE) {
        int eid = perm[p0_ + tid];
        leid[tid]  = eid;
        lsend[tid] = senders[eid];
        lrecv[tid] = receivers[eid];
        float vx = vectors[(size_t)eid * 3 + 0];
        float vy = vectors[(size_t)eid * 3 + 1];
        float vz = vectors[(size_t)eid * 3 + 2];
        float rn = 1.0f / (sqrtf(vx*vx + vy*vy + vz*vz) + 1e-9f);
        lY[tid][0] = vx * rn; lY[tid][1] = vy * rn; lY[tid][2] = vz * rn;
    }
    for (int i = tid; i < NWIN * FCH; i += 256) {
        laccS[i] = 0.f; laccV0[i] = 0.f; laccV1[i] = 0.f; laccV2[i] = 0.f;
    }
    __syncthreads();
    for (int idx = tid; idx < CE * NBASIS; idx += 256)
        lrad[idx] = radial[(size_t)leid[idx >> 3] * NBASIS + (idx & 7)];
    __syncthreads();   // barrier #2 (last before flush)

    // ---- radial MLP, wave-private rows [grp*16, +16), in-place in hA ----
    const int k    = tid & 63;
    const int grp  = tid >> 6;
    const int e_lo = grp * 16;

    {   // layer 1 (8->64)
        float w1c[NBASIS];
        #pragma unroll
        for (int j = 0; j < NBASIS; ++j) w1c[j] = w1[j * HDIM + k];
        #pragma unroll 4
        for (int e = 0; e < 16; ++e) {
            const float* r = &lrad[(e_lo + e) * NBASIS];
            float a = r[0]*w1c[0] + r[1]*w1c[1] + r[2]*w1c[2] + r[3]*w1c[3]
                    + r[4]*w1c[4] + r[5]*w1c[5] + r[6]*w1c[6] + r[7]*w1c[7];
            hA[(e_lo + e) * HDIM + k] = silu(a * INV_SQRT8);
        }
    }
    {   // layer 2 (64->64): j-outer, acc[16]
        float acc[16];
        #pragma unroll
        for (int e = 0; e < 16; ++e) acc[e] = 0.f;
        #pragma unroll 2
        for (int j = 0; j < HDIM; j += 4) {
            float wa = w2[(j+0) * HDIM + k];
            float wb = w2[(j+1) * HDIM + k];
            float wc = w2[(j+2) * HDIM + k];
            float wd = w2[(j+3) * HDIM + k];
            #pragma unroll
            for (int e = 0; e < 16; ++e) {
                float4 h = *(float4*)&hA[(e_lo + e) * HDIM + j];
                acc[e] += h.x*wa + h.y*wb + h.z*wc + h.w*wd;
            }
        }
        #pragma unroll
        for (int e = 0; e < 16; ++e)
            hA[(e_lo + e) * HDIM + k] = silu(acc[e] * INV_64);
    }
    {   // layer 3 (64->64)
        float acc[16];
        #pragma unroll
        for (int e = 0; e < 16; ++e) acc[e] = 0.f;
        #pragma unroll 2
        for (int j = 0; j < HDIM; j += 4) {
            float wa = w3[(j+0) * HDIM + k];
            float wb = w3[(j+1) * HDIM + k];
            float wc = w3[(j+2) * HDIM + k];
            float wd = w3[(j+3) * HDIM + k];
            #pragma unroll
            for (int e = 0; e < 16; ++e) {
                float4 h = *(float4*)&hA[(e_lo + e) * HDIM + j];
                acc[e] += h.x*wa + h.y*wb + h.z*wc + h.w*wd;
            }
        }
        #pragma unroll
        for (int e = 0; e < 16; ++e)
            hA[(e_lo + e) * HDIM + k] = silu(acc[e] * INV_64);
    }

    // ---- path passes (8 groups x 8 edges) ----
    const int fq = (tid & 31) * 4;
    const int eg = tid >> 5;
    const int eb = eg * 8;
    const int r0 = lrecv[0];
    const float* w4q = w4 + fq;

    // ===== pass p0: scalar path, aS =====
    {
        float m[8][4];
        #pragma unroll
        for (int q = 0; q < 8; ++q)
            #pragma unroll
            for (int c = 0; c < 4; ++c) m[q][c] = 0.f;
        #pragma unroll 2
        for (int j = 0; j < HDIM; j += 2) {
            float4 wa = *(const float4*)(w4q + (size_t)(j+0) * MIXW);
            float4 wb = *(const float4*)(w4q + (size_t)(j+1) * MIXW);
            #pragma unroll
            for (int q = 0; q < 8; ++q) {
                float2 h = *(float2*)&hA[(eb + q) * HDIM + j];
                m[q][0] += h.x*wa.x + h.y*wb.x;
                m[q][1] += h.x*wa.y + h.y*wb.y;
                m[q][2] += h.x*wa.z + h.y*wb.z;
                m[q][3] += h.x*wa.w + h.y*wb.w;
            }
        }
        float aS0,aS1,aS2,aS3; ZERO_S();
        int cur = lrecv[eb] - r0;
        #pragma unroll
        for (int q = 0; q < 8; ++q) {
            const int e  = eb + q;
            const int nl = lrecv[e] - r0;
            if (nl != cur) { FLUSH_S(); ZERO_S(); cur = nl; }
            float4 t4 = *(const float4*)(hs + (size_t)lsend[e] * FCH + fq);
            aS0 += m[q][0] * t4.x * INV_64;
            aS1 += m[q][1] * t4.y * INV_64;
            aS2 += m[q][2] * t4.z * INV_64;
            aS3 += m[q][3] * t4.w * INV_64;
        }
        FLUSH_S();
    }

    // ===== pass p2: es -> vector (x Y), aV =====
    {
        float m[8][4];
        #pragma unroll
        for (int q = 0; q < 8; ++q)
            #pragma unroll
            for (int c = 0; c < 4; ++c) m[q][c] = 0.f;
        #pragma unroll 2
        for (int j = 0; j < HDIM; j += 2) {
            float4 wa = *(const float4*)(w4q + (size_t)(j+0) * MIXW + 2*FCH);
            float4 wb = *(const float4*)(w4q + (size_t)(j+1) * MIXW + 2*FCH);
            #pragma unroll
            for (int q = 0; q < 8; ++q) {
                float2 h = *(float2*)&hA[(eb + q) * HDIM + j];
                m[q][0] += h.x*wa.x + h.y*wb.x;
                m[q][1] += h.x*wa.y + h.y*wb.y;
                m[q][2] += h.x*wa.z + h.y*wb.z;
                m[q][3] += h.x*wa.w + h.y*wb.w;
            }
        }
        float aV00,aV01,aV02,aV03, aV10,aV11,aV12,aV13, aV20,aV21,aV22,aV23;
        ZERO_V();
        int cur = lrecv[eb] - r0;
        #pragma unroll
        for (int q = 0; q < 8; ++q) {
            const int e  = eb + q;
            const int nl = lrecv[e] - r0;
            if (nl != cur) { FLUSH_V(); ZERO_V(); cur = nl; }
            float4 t4 = *(const float4*)(hs + (size_t)lsend[e] * FCH + fq);
            const float Yx = lY[e][0], Yy = lY[e][1], Yz = lY[e][2];
            float t0 = m[q][0] * t4.x * INV_64;
            float t1 = m[q][1] * t4.y * INV_64;
            float t2 = m[q][2] * t4.z * INV_64;
            float t3 = m[q][3] * t4.w * INV_64;
            aV00 += t0*Yx; aV01 += t1*Yx; aV02 += t2*Yx; aV03 += t3*Yx;
            aV10 += t0*Yy; aV11 += t1*Yy; aV12 += t2*Yy; aV13 += t3*Yy;
            aV20 += t0*Yz; aV21 += t1*Yz; aV22 += t2*Yz; aV23 += t3*Yz;
        }
        FLUSH_V();
    }

    // ===== pass p1: ev . Y -> scalar, aS =====
    {
        float m[8][4];
        #pragma unroll
        for (int q = 0; q < 8; ++q)
            #pragma unroll
            for (int c = 0; c < 4; ++c) m[q][c] = 0.f;
        #pragma unroll 2
        for (int j = 0; j < HDIM; j += 2) {
            float4 wa = *(const float4*)(w4q + (size_t)(j+0) * MIXW + 1*FCH);
            float4 wb = *(const float4*)(w4q + (size_t)(j+1) * MIXW + 1*FCH);
            #pragma unroll
            for (int q = 0; q < 8; ++q) {
                float2 h = *(float2*)&hA[(eb + q) * HDIM + j];
                m[q][0] += h.x*wa.x + h.y*wb.x;
                m[q][1] += h.x*wa.y + h.y*wb.y;
                m[q][2] += h.x*wa.z + h.y*wb.z;
                m[q][3] += h.x*wa.w + h.y*wb.w;
            }
        }
        float aS0,aS1,aS2,aS3; ZERO_S();
        int cur = lrecv[eb] - r0;
        #pragma unroll
        for (int q = 0; q < 8; ++q) {
            const int e  = eb + q;
            const int nl = lrecv[e] - r0;
            if (nl != cur) { FLUSH_S(); ZERO_S(); cur = nl; }
            const size_t so = (size_t)lsend[e] * FCH + fq;
            float4 t0 = *(const float4*)(hv0 + so);
            float4 t1 = *(const float4*)(hv1 + so);
            float4 t2 = *(const float4*)(hv2 + so);
            const float Yx = lY[e][0], Yy = lY[e][1], Yz = lY[e][2];
            aS0 += m[q][0] * (t0.x*Yx + t1.x*Yy + t2.x*Yz) * C_P1;
            aS1 += m[q][1] * (t0.y*Yx + t1.y*Yy + t2.y*Yz) * C_P1;
            aS2 += m[q][2] * (t0.z*Yx + t1.z*Yy + t2.z*Yz) * C_P1;
            aS3 += m[q][3] * (t0.w*Yx + t1.w*Yy + t2.w*Yz) * C_P1;
        }
        FLUSH_S();
    }

    // ===== pass p3: ev identity, aV (two 4-edge halves) =====
    {
        float aV00,aV01,aV02,aV03, aV10,aV11,aV12,aV13, aV20,aV21,aV22,aV23;
        ZERO_V();
        int cur = lrecv[eb] - r0;
        #pragma unroll
        for (int half = 0; half < 2; ++half) {
            const int e0 = eb + half * 4;
            float m[4][4];
            #pragma unroll
            for (int q = 0; q < 4; ++q)
                #pragma unroll
                for (int c = 0; c < 4; ++c) m[q][c] = 0.f;
            #pragma unroll 4
            for (int j = 0; j < HDIM; ++j) {
                float4 wa = *(const float4*)(w4q + (size_t)j * MIXW + 3*FCH);
                #pragma unroll
                for (int q = 0; q < 4; ++q) {
                    float h = hA[(e0 + q) * HDIM + j];
                    m[q][0] += h*wa.x; m[q][1] += h*wa.y;
                    m[q][2] += h*wa.z; m[q][3] += h*wa.w;
                }
            }
            #pragma unroll
            for (int q = 0; q < 4; ++q) {
                const int e  = e0 + q;
                const int nl = lrecv[e] - r0;
                if (nl != cur) { FLUSH_V(); ZERO_V(); cur = nl; }
                const size_t so = (size_t)lsend[e] * FCH + fq;
                float4 t0 = *(const float4*)(hv0 + so);
                float4 t1 = *(const float4*)(hv1 + so);
                float4 t2 = *(const float4*)(hv2 + so);
                float m0 = m[q][0]*INV_64, m1v = m[q][1]*INV_64;
                float m2v = m[q][2]*INV_64, m3v = m[q][3]*INV_64;
                aV00 += m0*t0.x; aV01 += m1v*t0.y; aV02 += m2v*t0.z; aV03 += m3v*t0.w;
                aV10 += m0*t1.x; aV11 += m1v*t1.y; aV12 += m2v*t1.z; aV13 += m3v*t1.w;
                aV20 += m0*t2.x; aV21 += m1v*t2.y; aV22 += m2v*t2.z; aV23 += m3v*t2.w;
            }
        }
        FLUSH_V();
    }

    // ===== pass p4: cross(ev, Y), aV (two 4-edge halves) =====
    {
        float aV00,aV01,aV02,aV03, aV10,aV11,aV12,aV13, aV20,aV21,aV22,aV23;
        ZERO_V();
        int cur = lrecv[eb] - r0;
        #pragma unroll
        for (int half = 0; half < 2; ++half) {
            const int e0 = eb + half * 4;
            float m[4][4];
            #pragma unroll
            for (int q = 0; q < 4; ++q)
                #pragma unroll
                for (int c = 0; c < 4; ++c) m[q][c] = 0.f;
            #pragma unroll 4
            for (int j = 0; j < HDIM; ++j) {
                float4 wa = *(const float4*)(w4q + (size_t)j * MIXW + 4*FCH);
                #pragma unroll
                for (int q = 0; q < 4; ++q) {
                    float h = hA[(e0 + q) * HDIM + j];
                    m[q][0] += h*wa.x; m[q][1] += h*wa.y;
                    m[q][2] += h*wa.z; m[q][3] += h*wa.w;
                }
            }
            #pragma unroll
            for (int q = 0; q < 4; ++q) {
                const int e  = e0 + q;
                const int nl = lrecv[e] - r0;
                if (nl != cur) { FLUSH_V(); ZERO_V(); cur = nl; }
                const size_t so = (size_t)lsend[e] * FCH + fq;
                float4 t0 = *(const float4*)(hv0 + so);
                float4 t1 = *(const float4*)(hv1 + so);
                float4 t2 = *(const float4*)(hv2 + so);
                const float Yx = lY[e][0], Yy = lY[e][1], Yz = lY[e][2];
                {   float m4v = m[q][0] * C_P4;
                    aV00 += m4v*(t1.x*Yz - t2.x*Yy);
                    aV10 += m4v*(t2.x*Yx - t0.x*Yz);
                    aV20 += m4v*(t0.x*Yy - t1.x*Yx); }
                {   float m4v = m[q][1] * C_P4;
                    aV01 += m4v*(t1.y*Yz - t2.y*Yy);
                    aV11 += m4v*(t2.y*Yx - t0.y*Yz);
                    aV21 += m4v*(t0.y*Yy - t1.y*Yx); }
                {   float m4v = m[q][2] * C_P4;
                    aV02 += m4v*(t1.z*Yz - t2.z*Yy);
                    aV12 += m4v*(t2.z*Yx - t0.z*Yz);
                    aV22 += m4v*(t0.z*Yy - t1.z*Yx); }
                {   float m4v = m[q][3] * C_P4;
                    aV03 += m4v*(t1.w*Yz - t2.w*Yy);
                    aV13 += m4v*(t2.w*Yx - t0.w*Yz);
                    aV23 += m4v*(t0.w*Yy - t1.w*Yx); }
            }
        }
        FLUSH_V();
    }

    __syncthreads();   // barrier #3: window complete
    int span = lrecv[CE - 1] - r0;
    if (span > NWIN - 1) span = NWIN - 1;
    const int tot = (span + 1) * FCH;
    for (int i = tid; i < tot; i += 256) {
        const size_t go = (size_t)(r0 + (i >> 7)) * FCH + (i & 127);
        atomicAdd(&agg_s[go],  laccS[i]);
        atomicAdd(&agg_v0[go], laccV0[i]);
        atomicAdd(&agg_v1[go], laccV1[i]);
        atomicAdd(&agg_v2[go], laccV2[i]);
    }
}

// ---------------------------------------------------------------- K3: epilogue
__global__ __launch_bounds__(128) void k_epilogue(
    const float* __restrict__ agg_s, const float* __restrict__ agg_v0,
    const float* __restrict__ agg_v1, const float* __restrict__ agg_v2,
    const float* __restrict__ self_conn, const int* __restrict__ species,
    const float* __restrict__ w_down0, const float* __restrict__ w_down1,
    const float* __restrict__ w_sc, const float* __restrict__ w_post,
    const float* __restrict__ w_read1, const float* __restrict__ w_read2,
    float* __restrict__ out0, float* __restrict__ feats_out)
{
    __shared__ float lS[NT1][FCH];
    __shared__ float lV[3][NT1][FCH];
    __shared__ float fA[NT1][FCH];
    __shared__ float fB[NT1][FCH];
    __shared__ int lsp[NT1];
    const int g  = threadIdx.x;
    const int n0 = blockIdx.x * NT1;

    #pragma unroll
    for (int n = 0; n < NT1; ++n) {
        size_t o = (size_t)(n0 + n) * FCH + g;
        lS[n][g]    = agg_s[o]  * EPSN;
        lV[0][n][g] = agg_v0[o] * EPSN;
        lV[1][n][g] = agg_v1[o] * EPSN;
        lV[2][n][g] = agg_v2[o] * EPSN;
    }
    if (g < NT1) lsp[g] = species[n0 + g];
    __syncthreads();

    float xs[NT1], xv0[NT1], xv1[NT1], xv2[NT1];
    #pragma unroll
    for (int n = 0; n < NT1; ++n) { xs[n]=0; xv0[n]=0; xv1[n]=0; xv2[n]=0; }
    #pragma unroll 2
    for (int f = 0; f < FCH; ++f) {
        float d0 = w_down0[f * FCH + g];
        float d1 = w_down1[f * FCH + g];
        #pragma unroll
        for (int n = 0; n < NT1; ++n) {
            xs[n]  += lS[n][f] * d0;
            xv0[n] += lV[0][n][f] * d1;
            xv1[n] += lV[1][n][f] * d1;
            xv2[n] += lV[2][n][f] * d1;
        }
    }
    #pragma unroll
    for (int n = 0; n < NT1; ++n) {
        float s  = xs[n]  * INV_SQRT128;
        float v0 = xv0[n] * INV_SQRT128;
        float v1 = xv1[n] * INV_SQRT128;
        float v2 = xv2[n] * INV_SQRT128;
        int z = lsp[n];
        float wz0 = w_sc[((size_t)z * 3 + 0) * FCH + g] * INV_SQRT10;
        float wz1 = w_sc[((size_t)z * 3 + 1) * FCH + g] * INV_SQRT10;
        float wz2 = w_sc[((size_t)z * 3 + 2) * FCH + g] * INV_SQRT10;
        fA[n][g] = wz0 * s + wz1 * s * s + wz2 * (v0*v0 + v1*v1 + v2*v2);
    }
    __syncthreads();

    float fc[NT1];
    #pragma unroll
    for (int n = 0; n < NT1; ++n) fc[n] = 0;
    #pragma unroll 2
    for (int f = 0; f < FCH; ++f) {
        float wp = w_post[f * FCH + g];
        #pragma unroll
        for (int n = 0; n < NT1; ++n) fc[n] += fA[n][f] * wp;
    }
    #pragma unroll
    for (int n = 0; n < NT1; ++n) {
        size_t o = (size_t)(n0 + n) * FCH + g;
        float v = fc[n] * INV_SQRT128 + self_conn[o];
        fB[n][g] = v;
        feats_out[o] = v;
    }
    __syncthreads();

    const int n2 = g >> 4, r = g & 15;
    float acc = 0.f;
    for (int f = 0; f < FCH; ++f) acc += fB[n2][f] * w_read1[f * 16 + r];
    float t = silu(acc * INV_SQRT128);
    float val = t * w_read2[r];
    val += __shfl_down(val, 8, 16);
    val += __shfl_down(val, 4, 16);
    val += __shfl_down(val, 2, 16);
    val += __shfl_down(val, 1, 16);
    if (r == 0) out0[n0 + n2] = val * INV_SQRT16;
}

// ---------------------------------------------------------------- launch
extern "C" void kernel_launch(void* const* d_in, const int* in_sizes, int n_in,
                              void* d_out, int out_size, void* d_ws, size_t ws_size,
                              hipStream_t stream) {
    (void)in_sizes; (void)n_in; (void)out_size; (void)ws_size;
    const float* vectors      = (const float*)d_in[0];
    const float* node_scalars = (const float*)d_in[1];
    const float* node_vectors = (const float*)d_in[2];
    const float* radial       = (const float*)d_in[3];
    const float* w_skip       = (const float*)d_in[4];
    const float* w_up0        = (const float*)d_in[5];
    const float* w_up1        = (const float*)d_in[6];
    const float* mlp_w1       = (const float*)d_in[7];
    const float* mlp_w2       = (const float*)d_in[8];
    const float* mlp_w3       = (const float*)d_in[9];
    const float* mlp_w4       = (const float*)d_in[10];
    const float* w_down0      = (const float*)d_in[11];
    const float* w_down1      = (const float*)d_in[12];
    const float* w_sc         = (const float*)d_in[13];
    const float* w_post       = (const float*)d_in[14];
    const float* w_read1      = (const float*)d_in[15];
    const float* w_read2      = (const float*)d_in[16];
    const int*   senders      = (const int*)d_in[17];
    const int*   receivers    = (const int*)d_in[18];
    const int*   species      = (const int*)d_in[19];

    const size_t NF = (size_t)N_NODES * FCH;
    float* ws     = (float*)d_ws;
    float* hs     = ws;
    float* hv0    = ws + 1 * NF;
    float* hv1    = ws + 2 * NF;
    float* hv2    = ws + 3 * NF;
    float* agg_s  = ws + 4 * NF;
    float* agg_v0 = ws + 5 * NF;
    float* agg_v1 = ws + 6 * NF;
    float* agg_v2 = ws + 7 * NF;
    int* counts   = (int*)(ws + 8 * NF);      // [N]
    int* cursor   = counts + N_NODES;         // [N]
    int* perm     = cursor + N_NODES;         // [E]

    float* out       = (float*)d_out;
    float* feats     = out + N_NODES;   // final feats output
    float* self_conn = feats;           // scratch until epilogue overwrites

    hipMemsetAsync(counts, 0, N_NODES * sizeof(int), stream);
    hipMemsetAsync(agg_s, 0, 4 * NF * sizeof(float), stream);

    k_node_pre<<<N_NODES / NT1, 128, 0, stream>>>(
        node_scalars, node_vectors, w_skip, w_up0, w_up1, species,
        hs, hv0, hv1, hv2, self_conn);

    k_hist<<<N_EDGES / 256, 256, 0, stream>>>(receivers, counts);
    k_scan<<<1, 1024, 0, stream>>>(counts, cursor);
    k_permute<<<N_EDGES / 256, 256, 0, stream>>>(receivers, cursor, perm);

    k_edge<<<N_EDGES / CE, 256, 0, stream>>>(
        vectors, radial, mlp_w1, mlp_w2, mlp_w3, mlp_w4,
        hs, hv0, hv1, hv2, senders, receivers, perm,
        agg_s, agg_v0, agg_v1, agg_v2);

    k_epilogue<<<N_NODES / NT1, 128, 0, stream>>>(
        agg_s, agg_v0, agg_v1, agg_v2, self_conn, species,
        w_down0, w_down1, w_sc, w_post, w_read1, w_read2,
        out, feats);
}